// Round 6
// baseline (11497.210 us; speedup 1.0000x reference)
//
#include <hip/hip_runtime.h>
#include <hip/hip_bf16.h>
#include <hip/hip_cooperative_groups.h>

namespace cg = cooperative_groups;

#define TT 8
#define NN 10000
#define EE 320000
#define NG 64

typedef short v8s __attribute__((ext_vector_type(8)));
typedef float v4f __attribute__((ext_vector_type(4)));

__device__ __forceinline__ float sigmf(float x){ return 1.f/(1.f+expf(-x)); }
__device__ __forceinline__ short f2bf(float f){
  unsigned u=__float_as_uint(f);
  unsigned r=(u + 0x7FFFu + ((u>>16)&1u))>>16;
  return (short)r;
}
__device__ __forceinline__ float bf2f(short s){
  return __uint_as_float(((unsigned)(unsigned short)s)<<16);
}

// ---------- setup ----------
__global__ void k_deg(const int* __restrict__ src, const float* __restrict__ ea, float* __restrict__ deg){
  int e = blockIdx.x*256 + threadIdx.x;
  if(e<EE) atomicAdd(&deg[src[e]], ea[e]);
}

__global__ void k_dis(const float* __restrict__ deg, float* __restrict__ dis){
  int n = blockIdx.x*256+threadIdx.x;
  if(n<NN){ float d=deg[n]; dis[n] = d>0.f ? rsqrtf(d) : 0.f; }
}

__global__ void k_wnorm(const int* __restrict__ src, const int* __restrict__ dst, const float* __restrict__ ea,
                        const float* __restrict__ dis, float* __restrict__ wnorm, int* __restrict__ cnt){
  int e = blockIdx.x*256+threadIdx.x;
  if(e<EE){
    int s=src[e], d=dst[e];
    wnorm[e] = dis[s]*ea[e]*dis[d];
    atomicAdd(&cnt[d],1);
  }
}

__global__ __launch_bounds__(1024) void k_scan(const int* __restrict__ cnt, int* __restrict__ rowptr, int* __restrict__ wp){
  __shared__ int wsum[16];
  __shared__ int carrysh;
  int tid=threadIdx.x, lane=tid&63, wv=tid>>6;
  if(tid==0){ carrysh=0; rowptr[0]=0; }
  __syncthreads();
  for(int base=0;base<NN;base+=1024){
    int i=base+tid;
    int v=(i<NN)?cnt[i]:0;
    int s=v;
    #pragma unroll
    for(int d=1;d<64;d<<=1){ int t=__shfl_up(s,d,64); if(lane>=d) s+=t; }
    if(lane==63) wsum[wv]=s;
    __syncthreads();
    if(wv==0 && lane<16){
      int t=wsum[lane]; int ss=t;
      #pragma unroll
      for(int d=1;d<16;d<<=1){ int u=__shfl_up(ss,d,64); if(lane>=d) ss+=u; }
      wsum[lane]=ss-t;
    }
    __syncthreads();
    int total = carrysh + wsum[wv] + s;
    if(i<NN) rowptr[i+1]=total;
    __syncthreads();
    if(tid==1023) carrysh = total;
    __syncthreads();
  }
  for(int i=tid;i<NN;i+=1024) wp[i]=rowptr[i];
}

__global__ void k_scatter(const int* __restrict__ src, const int* __restrict__ dst, const float* __restrict__ wnorm,
                          int* __restrict__ wp, int2* __restrict__ pack){
  int e = blockIdx.x*256+threadIdx.x;
  if(e<EE){
    int d=dst[e];
    int pos = atomicAdd(&wp[d],1);
    pack[pos] = make_int2(src[e], __float_as_int(wnorm[e]));
  }
}

// fetch original combined-K weights
__device__ __forceinline__ float fetchW1(const float* Wx, const float* Wh, int kk, int col){
  int g=col>>5, j=col&31;
  if(kk<160){ int k=kk>>5, i=kk&31; return Wx[((g*5+k)*32+i)*32+j]; }
  int rr=kk-160; int k=rr>>5, i=rr&31; return Wh[((g*5+k)*32+i)*32+j];
}
__device__ __forceinline__ float fetchW2(const float* Wx, const float* Wh, int kk, int col){
  int g=col>>4, j=col&15;
  if(kk<160){ int k=kk>>5, i=kk&31; return Wx[((g*5+k)*32+i)*16+j]; }
  if(kk<240){ int rr=kk-160; int k=rr>>4, i=rr&15; return Wh[((g*5+k)*16+i)*16+j]; }
  return 0.f;
}

// Pack W into MFMA B-fragments with k-map phi(kt,g,reg) = kt*32 + 8*g + reg.
__global__ void k_wreorg(const float* __restrict__ Wx1,const float* __restrict__ bx1,
                         const float* __restrict__ Wh1,const float* __restrict__ bh1,const float* __restrict__ b1,
                         const float* __restrict__ Wx2,const float* __restrict__ bx2,
                         const float* __restrict__ Wh2,const float* __restrict__ bh2,const float* __restrict__ b2g,
                         short* __restrict__ Wpk1, short* __restrict__ Wpk2,
                         float* __restrict__ Bc1,float* __restrict__ Bc2){
  int idx = blockIdx.x*256+threadIdx.x;
  if(idx < 10240){
    int lane=idx&63, rest=idx>>6;
    int nt=rest&7, s=(rest>>3)&1, kt=rest>>4;
    int col = nt*16 + (lane&15);
    int g = lane>>4;
    short out[8];
    #pragma unroll
    for(int j=0;j<8;j++){
      int kk = kt*32 + 8*g + j;
      float w = fetchW1(Wx1,Wh1,kk,col);
      short hi = f2bf(w);
      out[j] = (s==0)? hi : f2bf(w - bf2f(hi));
    }
    #pragma unroll
    for(int j=0;j<8;j++) Wpk1[(size_t)idx*8+j]=out[j];
  } else if(idx < 14336){
    int t=idx-10240;
    int lane=t&63, rest=t>>6;
    int nt=rest&3, s=(rest>>2)&1, kt=rest>>3;
    int col = nt*16 + (lane&15);
    int g = lane>>4;
    short out[8];
    #pragma unroll
    for(int j=0;j<8;j++){
      int kk = kt*32 + 8*g + j;
      float w = fetchW2(Wx2,Wh2,kk,col);
      short hi = f2bf(w);
      out[j] = (s==0)? hi : f2bf(w - bf2f(hi));
    }
    #pragma unroll
    for(int j=0;j<8;j++) Wpk2[(size_t)t*8+j]=out[j];
  } else if(idx < 14464){
    int i=idx-14336; int g=i>>5,j=i&31;
    Bc1[i]=bx1[g*32+j]+bh1[g*32+j]+b1[g*32+j];
  } else if(idx < 14528){
    int i=idx-14464; int g=i>>4,j=i&15;
    Bc2[i]=bx2[g*16+j]+bh2[g*16+j]+b2g[g*16+j];
  }
}

// ---------- fused recurrent loop (cooperative) ----------
struct KArgs {
  const float* x;
  float* Z1; float* Z2;
  const int* rowptr; const int2* pack;
  const short* Wpk1; const short* Wpk2;
  const float* Bc1; const float* Bc2;
  const float* wc1; const float* wc2;
  float* c1; float* c2; float* h2;
  const int* batch; float* u;
  const float* lw; const float* lb; float* out;
};

template<int STRIDE,int NA,int NB>
__device__ __forceinline__ void spmm_phase(const int* __restrict__ rowptr, const int2* __restrict__ pack,
    float* __restrict__ Z, int cinA,int coutA,int cppA,int cinB,int coutB,int cppB,
    float alpha,float beta,int gwave,int nwaves,int lane){
  const int hA=NA/2, hB=NB/2;
  bool act = lane < hA+hB;
  int cin  = lane<hA ? cinA+2*lane : cinB+2*(lane-hA);
  int cout = lane<hA ? coutA+2*lane : coutB+2*(lane-hA);
  int cpp  = lane<hA ? cppA +2*lane : cppB+2*(lane-hA);
  if(!act) cin=0;
  const float* __restrict__ Zc = Z + cin;
  for(int wid=gwave; wid<NN; wid+=nwaves){
    int e0=rowptr[wid], e1=rowptr[wid+1];
    float accx=0.f, accy=0.f;
    int e=e0;
    for(; e+16<=e1; e+=16){
      float w[16]; float2 z[16];
      #pragma unroll
      for(int j=0;j<16;j++){
        int2 p=pack[e+j];
        w[j]=__int_as_float(p.y);
        z[j]=*(const float2*)&Zc[(unsigned)p.x*STRIDE];
      }
      #pragma unroll
      for(int j=0;j<16;j++){ accx += w[j]*z[j].x; accy += w[j]*z[j].y; }
    }
    for(; e+4<=e1; e+=4){
      float w[4]; float2 z[4];
      #pragma unroll
      for(int j=0;j<4;j++){ int2 p=pack[e+j]; w[j]=__int_as_float(p.y); z[j]=*(const float2*)&Zc[(unsigned)p.x*STRIDE]; }
      #pragma unroll
      for(int j=0;j<4;j++){ accx += w[j]*z[j].x; accy += w[j]*z[j].y; }
    }
    for(; e<e1; ++e){
      int2 p=pack[e];
      float2 z=*(const float2*)&Zc[(unsigned)p.x*STRIDE];
      accx += __int_as_float(p.y)*z.x; accy += __int_as_float(p.y)*z.y;
    }
    if(act){
      float vx = -alpha*accx, vy = -alpha*accy;
      if(beta!=0.f){
        float2 pp=*(const float2*)&Z[(unsigned)wid*STRIDE+cpp];
        vx += beta*pp.x; vy += beta*pp.y;
      }
      *(float2*)&Z[(unsigned)wid*STRIDE+cout]=make_float2(vx,vy);
    }
  }
}

__device__ __forceinline__ void gemm1_phase(const KArgs& a, int gwave,int nwaves,int lane){
  const v8s* Wp=(const v8s*)a.Wpk1;
  int m=lane&15, g=lane>>4;
  for(int tile=gwave; tile<625; tile+=nwaves){
    int row0=tile*16;
    const float* arow = a.Z1 + (size_t)(row0+m)*320;
    v4f acc[8];
    #pragma unroll
    for(int nt=0;nt<8;nt++) acc[nt]=(v4f){0.f,0.f,0.f,0.f};
    #pragma unroll
    for(int kt=0;kt<10;kt++){
      float4 a0=*(const float4*)&arow[kt*32+8*g];
      float4 a1=*(const float4*)&arow[kt*32+8*g+4];
      float av[8]={a0.x,a0.y,a0.z,a0.w,a1.x,a1.y,a1.z,a1.w};
      v8s ah, al;
      #pragma unroll
      for(int j=0;j<8;j++){
        short hi=f2bf(av[j]);
        ah[j]=hi; al[j]=f2bf(av[j]-bf2f(hi));
      }
      int baseh = kt*1024 + lane;
      #pragma unroll
      for(int nt=0;nt<8;nt++){
        v8s bh = Wp[baseh + nt*64];
        v8s bl = Wp[baseh + 512 + nt*64];
        acc[nt]=__builtin_amdgcn_mfma_f32_16x16x32_bf16(ah,bh,acc[nt],0,0,0);
        acc[nt]=__builtin_amdgcn_mfma_f32_16x16x32_bf16(al,bh,acc[nt],0,0,0);
        acc[nt]=__builtin_amdgcn_mfma_f32_16x16x32_bf16(ah,bl,acc[nt],0,0,0);
      }
    }
    int j0=lane&15;
    int r0=row0+(lane>>4)*4;
    #pragma unroll
    for(int reg=0;reg<4;reg++){
      int row=r0+reg;
      #pragma unroll
      for(int jj=0;jj<2;jj++){
        int j=jj*16+j0;
        float c=a.c1[row*32+j];
        float I =sigmf(acc[0+jj][reg]+a.Bc1[j]      + a.wc1[j]*c);
        float Fg=sigmf(acc[2+jj][reg]+a.Bc1[32+j]   + a.wc1[32+j]*c);
        float Ct=tanhf(acc[4+jj][reg]+a.Bc1[64+j]);
        float Cn=Fg*c + I*Ct;
        float O =sigmf(acc[6+jj][reg]+a.Bc1[96+j]   + a.wc1[64+j]*Cn);
        float h =O*tanhf(Cn);
        a.c1[row*32+j]=Cn;
        a.Z1[(size_t)row*320+160+j]=h;   // next-step layer-1 H-chain T0
        a.Z2[(size_t)row*240+j]=h;       // this-step layer-2 X-chain T0
      }
    }
  }
}

__device__ __forceinline__ void gemm2_phase(const KArgs& a, const float* xn, int gwave,int nwaves,int lane){
  const v8s* Wp=(const v8s*)a.Wpk2;
  int m=lane&15, g=lane>>4;
  for(int tile=gwave; tile<625; tile+=nwaves){
    int row0=tile*16;
    const float* arow = a.Z2 + (size_t)(row0+m)*240;
    v4f acc[4];
    #pragma unroll
    for(int nt=0;nt<4;nt++) acc[nt]=(v4f){0.f,0.f,0.f,0.f};
    #pragma unroll
    for(int kt=0;kt<8;kt++){
      float4 a0=*(const float4*)&arow[kt*32+8*g];
      float4 a1=*(const float4*)&arow[kt*32+8*g+4];
      float av[8]={a0.x,a0.y,a0.z,a0.w,a1.x,a1.y,a1.z,a1.w};
      v8s ah, al;
      #pragma unroll
      for(int j=0;j<8;j++){
        short hi=f2bf(av[j]);
        ah[j]=hi; al[j]=f2bf(av[j]-bf2f(hi));
      }
      int baseh = kt*512 + lane;
      #pragma unroll
      for(int nt=0;nt<4;nt++){
        v8s bh = Wp[baseh + nt*64];
        v8s bl = Wp[baseh + 256 + nt*64];
        acc[nt]=__builtin_amdgcn_mfma_f32_16x16x32_bf16(ah,bh,acc[nt],0,0,0);
        acc[nt]=__builtin_amdgcn_mfma_f32_16x16x32_bf16(al,bh,acc[nt],0,0,0);
        acc[nt]=__builtin_amdgcn_mfma_f32_16x16x32_bf16(ah,bl,acc[nt],0,0,0);
      }
    }
    int j=lane&15;
    int r0=row0+(lane>>4)*4;
    #pragma unroll
    for(int reg=0;reg<4;reg++){
      int row=r0+reg;
      float c=a.c2[row*16+j];
      float I =sigmf(acc[0][reg]+a.Bc2[j]    +a.wc2[j]*c);
      float Fg=sigmf(acc[1][reg]+a.Bc2[16+j] +a.wc2[16+j]*c);
      float Ct=tanhf(acc[2][reg]+a.Bc2[32+j]);
      float Cn=Fg*c+I*Ct;
      float O =sigmf(acc[3][reg]+a.Bc2[48+j] +a.wc2[32+j]*Cn);
      float h =O*tanhf(Cn);
      a.c2[row*16+j]=Cn; a.h2[row*16+j]=h;
      a.Z2[(size_t)row*240+160+j]=h;     // next-step layer-2 H-chain T0
      if(xn){
        float2 xv=*(const float2*)&xn[(size_t)row*32+j*2];
        *(float2*)&a.Z1[(size_t)row*320+j*2]=xv;   // next-step layer-1 X-chain T0
      }
    }
  }
}

__global__ __launch_bounds__(256,4) void k_loop(KArgs a){
  cg::grid_group grid = cg::this_grid();
  const int tid=threadIdx.x;
  const int lane=tid&63;
  const int wv=tid>>6;
  const int gwave=blockIdx.x*4+wv;
  const int nwaves=gridDim.x*4;
  const int gthread=blockIdx.x*256+tid;
  const int nthreads=gridDim.x*256;

  // phase 0: copy x[0] into Z1 X-T0 slot
  for(int idx=gthread; idx<NN*8; idx+=nthreads){
    int n=idx>>3, c=idx&7;
    float4 v=((const float4*)a.x)[idx];
    *(float4*)&a.Z1[(size_t)n*320+c*4]=v;
  }
  __threadfence();
  grid.sync();

  for(int t=0;t<TT;t++){
    for(int k=1;k<5;k++){
      float alpha=(k==1)?1.f:2.f, beta=(k==1)?0.f:-1.f;
      spmm_phase<320,32,32>(a.rowptr,a.pack,a.Z1,
        (k-1)*32, k*32, (k-2)*32,
        160+(k-1)*32, 160+k*32, 160+(k-2)*32,
        alpha,beta,gwave,nwaves,lane);
      __threadfence(); grid.sync();
    }
    gemm1_phase(a,gwave,nwaves,lane);
    __threadfence(); grid.sync();
    for(int k=1;k<5;k++){
      float alpha=(k==1)?1.f:2.f, beta=(k==1)?0.f:-1.f;
      spmm_phase<240,32,16>(a.rowptr,a.pack,a.Z2,
        (k-1)*32, k*32, (k-2)*32,
        160+(k-1)*16, 160+k*16, 160+(k-2)*16,
        alpha,beta,gwave,nwaves,lane);
      __threadfence(); grid.sync();
    }
    gemm2_phase(a,(t<TT-1)? a.x+(size_t)(t+1)*NN*32 : nullptr,gwave,nwaves,lane);
    __threadfence(); grid.sync();
  }

  // pool
  for(int idx=gthread; idx<NN*16; idx+=nthreads){
    int n=idx>>4, j=idx&15;
    atomicAdd(&a.u[a.batch[n]*16+j], a.h2[idx]);
  }
  __threadfence();
  grid.sync();
  // final
  if(gthread<NG){
    int g=gthread;
    float s=a.lb[0];
    #pragma unroll
    for(int j=0;j<16;j++) s += a.u[g*16+j]*a.lw[j];
    a.out[g]=s;
  }
}

extern "C" void kernel_launch(void* const* d_in, const int* in_sizes, int n_in,
                              void* d_out, int out_size, void* d_ws, size_t ws_size,
                              hipStream_t stream){
  const float* x   = (const float*)d_in[0];
  const int*   ei  = (const int*)d_in[1];
  const float* ea  = (const float*)d_in[2];
  const int*   bat = (const int*)d_in[3];
  const float* Wx1=(const float*)d_in[4];  const float* bx1=(const float*)d_in[5];
  const float* Wh1=(const float*)d_in[6];  const float* bh1=(const float*)d_in[7];
  const float* wc1=(const float*)d_in[8];  const float* b1 =(const float*)d_in[9];
  const float* Wx2=(const float*)d_in[10]; const float* bx2=(const float*)d_in[11];
  const float* Wh2=(const float*)d_in[12]; const float* bh2=(const float*)d_in[13];
  const float* wc2=(const float*)d_in[14]; const float* b2 =(const float*)d_in[15];
  const float* lw =(const float*)d_in[16]; const float* lb =(const float*)d_in[17];
  const int* src = ei; const int* dst = ei+EE;

  float* ws = (float*)d_ws;
  size_t off=0;
  auto alloc=[&](size_t n)->float*{ float* p=ws+off; off+=(n+15)&~(size_t)15; return p; };
  // zeroed region: deg, c1, c2, u, cnt, Z1, Z2(+pad)
  float* deg=alloc(NN);
  float* c1=alloc((size_t)NN*32);
  float* c2=alloc((size_t)NN*16);
  float* u =alloc(NG*16);
  int*   cnt=(int*)alloc(NN);
  float* Z1=alloc((size_t)NN*320);
  float* Z2=alloc((size_t)NN*240+80);
  size_t zeroEnd=off;
  float* h2=alloc((size_t)NN*16);
  float* dis=alloc(NN);
  float* wnorm=alloc(EE);
  int*   rowptr=(int*)alloc(NN+1);
  int*   wp=(int*)alloc(NN);
  int2*  pack=(int2*)alloc((size_t)EE*2);
  short* Wpk1=(short*)alloc(10240*4);
  short* Wpk2=(short*)alloc(4096*4);
  float* Bc1=alloc(128);     float* Bc2=alloc(64);
  (void)ws_size; (void)in_sizes; (void)n_in; (void)out_size;

  hipMemsetAsync(d_ws, 0, zeroEnd*sizeof(float), stream);
  k_deg    <<<1250,256,0,stream>>>(src,ea,deg);
  k_dis    <<<40,256,0,stream>>>(deg,dis);
  k_wnorm  <<<1250,256,0,stream>>>(src,dst,ea,dis,wnorm,cnt);
  k_scan   <<<1,1024,0,stream>>>(cnt,rowptr,wp);
  k_scatter<<<1250,256,0,stream>>>(src,dst,wnorm,wp,pack);
  k_wreorg <<<57,256,0,stream>>>(Wx1,bx1,Wh1,bh1,b1,Wx2,bx2,Wh2,bh2,b2,Wpk1,Wpk2,Bc1,Bc2);

  KArgs ha;
  ha.x=x; ha.Z1=Z1; ha.Z2=Z2; ha.rowptr=rowptr; ha.pack=pack;
  ha.Wpk1=Wpk1; ha.Wpk2=Wpk2; ha.Bc1=Bc1; ha.Bc2=Bc2;
  ha.wc1=wc1; ha.wc2=wc2; ha.c1=c1; ha.c2=c2; ha.h2=h2;
  ha.batch=bat; ha.u=u; ha.lw=lw; ha.lb=lb; ha.out=(float*)d_out;

  int occ=0;
  hipOccupancyMaxActiveBlocksPerMultiprocessor(&occ, k_loop, 256, 0);
  if(occ<1) occ=1;
  int nb = occ*256;              // 256 CUs on MI355X
  if(nb>2048) nb=2048;

  void* params[] = { (void*)&ha };
  hipLaunchCooperativeKernel(k_loop, dim3(nb), dim3(256), params, 0, stream);
}

// Round 7
// 1292.423 us; speedup vs baseline: 8.8959x; 8.8959x over previous
//
#include <hip/hip_runtime.h>
#include <hip/hip_bf16.h>

#define TT 8
#define NN 10000
#define EE 320000
#define NG 64

typedef short v8s __attribute__((ext_vector_type(8)));
typedef float v4f __attribute__((ext_vector_type(4)));

__device__ __forceinline__ float sigmf(float x){ return 1.f/(1.f+expf(-x)); }
__device__ __forceinline__ short f2bf(float f){
  unsigned u=__float_as_uint(f);
  unsigned r=(u + 0x7FFFu + ((u>>16)&1u))>>16;
  return (short)r;
}
__device__ __forceinline__ float bf2f(short s){
  return __uint_as_float(((unsigned)(unsigned short)s)<<16);
}
// fragment index: Zb[((tile*TK+kt)*64 + g*16 + m)*8 + reg], c = kt*32 + 8g + reg, m = row&15
__device__ __forceinline__ size_t fragidx(int TK,int row,int c){
  int tile=row>>4, m=row&15, kt=c>>5, cc=c&31;
  return ((size_t)(tile*TK+kt)*64 + (cc>>3)*16 + m)*8 + (cc&7);
}

// ---------- setup ----------
__global__ void k_deg(const int* __restrict__ src, const float* __restrict__ ea, float* __restrict__ deg){
  int e = blockIdx.x*256 + threadIdx.x;
  if(e<EE) atomicAdd(&deg[src[e]], ea[e]);
}

__global__ void k_dis(const float* __restrict__ deg, float* __restrict__ dis){
  int n = blockIdx.x*256+threadIdx.x;
  if(n<NN){ float d=deg[n]; dis[n] = d>0.f ? rsqrtf(d) : 0.f; }
}

__global__ void k_wnorm(const int* __restrict__ src, const int* __restrict__ dst, const float* __restrict__ ea,
                        const float* __restrict__ dis, float* __restrict__ wnorm, int* __restrict__ cnt){
  int e = blockIdx.x*256+threadIdx.x;
  if(e<EE){
    int s=src[e], d=dst[e];
    wnorm[e] = dis[s]*ea[e]*dis[d];
    atomicAdd(&cnt[d],1);
  }
}

__global__ __launch_bounds__(1024) void k_scan(const int* __restrict__ cnt, int* __restrict__ rowptr, int* __restrict__ wp){
  __shared__ int wsum[16];
  __shared__ int carrysh;
  int tid=threadIdx.x, lane=tid&63, wv=tid>>6;
  if(tid==0){ carrysh=0; rowptr[0]=0; }
  __syncthreads();
  for(int base=0;base<NN;base+=1024){
    int i=base+tid;
    int v=(i<NN)?cnt[i]:0;
    int s=v;
    #pragma unroll
    for(int d=1;d<64;d<<=1){ int t=__shfl_up(s,d,64); if(lane>=d) s+=t; }
    if(lane==63) wsum[wv]=s;
    __syncthreads();
    if(wv==0 && lane<16){
      int t=wsum[lane]; int ss=t;
      #pragma unroll
      for(int d=1;d<16;d<<=1){ int u=__shfl_up(ss,d,64); if(lane>=d) ss+=u; }
      wsum[lane]=ss-t;
    }
    __syncthreads();
    int total = carrysh + wsum[wv] + s;
    if(i<NN) rowptr[i+1]=total;
    __syncthreads();
    if(tid==1023) carrysh = total;
    __syncthreads();
  }
  for(int i=tid;i<NN;i+=1024) wp[i]=rowptr[i];
}

__global__ void k_scatter(const int* __restrict__ src, const int* __restrict__ dst, const float* __restrict__ wnorm,
                          int* __restrict__ wp, int2* __restrict__ pack){
  int e = blockIdx.x*256+threadIdx.x;
  if(e<EE){
    int d=dst[e];
    int pos = atomicAdd(&wp[d],1);
    pack[pos] = make_int2(src[e], __float_as_int(wnorm[e]));
  }
}

// fetch original combined-K weights
__device__ __forceinline__ float fetchW1(const float* Wx, const float* Wh, int kk, int col){
  int g=col>>5, j=col&31;
  if(kk<160){ int k=kk>>5, i=kk&31; return Wx[((g*5+k)*32+i)*32+j]; }
  int rr=kk-160; int k=rr>>5, i=rr&31; return Wh[((g*5+k)*32+i)*32+j];
}
__device__ __forceinline__ float fetchW2(const float* Wx, const float* Wh, int kk, int col){
  int g=col>>4, j=col&15;
  if(kk<160){ int k=kk>>5, i=kk&31; return Wx[((g*5+k)*32+i)*16+j]; }
  if(kk<240){ int rr=kk-160; int k=rr>>4, i=rr&15; return Wh[((g*5+k)*16+i)*16+j]; }
  return 0.f;
}

// Pack W into MFMA B-fragments with k-map phi(kt,g,reg) = kt*32 + 8*g + reg.
__global__ void k_wreorg(const float* __restrict__ Wx1,const float* __restrict__ bx1,
                         const float* __restrict__ Wh1,const float* __restrict__ bh1,const float* __restrict__ b1,
                         const float* __restrict__ Wx2,const float* __restrict__ bx2,
                         const float* __restrict__ Wh2,const float* __restrict__ bh2,const float* __restrict__ b2g,
                         short* __restrict__ Wpk1, short* __restrict__ Wpk2,
                         float* __restrict__ Bc1,float* __restrict__ Bc2){
  int idx = blockIdx.x*256+threadIdx.x;
  if(idx < 10240){
    int lane=idx&63, rest=idx>>6;
    int nt=rest&7, s=(rest>>3)&1, kt=rest>>4;
    int col = nt*16 + (lane&15);
    int g = lane>>4;
    short out[8];
    #pragma unroll
    for(int j=0;j<8;j++){
      int kk = kt*32 + 8*g + j;
      float w = fetchW1(Wx1,Wh1,kk,col);
      short hi = f2bf(w);
      out[j] = (s==0)? hi : f2bf(w - bf2f(hi));
    }
    #pragma unroll
    for(int j=0;j<8;j++) Wpk1[(size_t)idx*8+j]=out[j];
  } else if(idx < 14336){
    int t=idx-10240;
    int lane=t&63, rest=t>>6;
    int nt=rest&3, s=(rest>>2)&1, kt=rest>>3;
    int col = nt*16 + (lane&15);
    int g = lane>>4;
    short out[8];
    #pragma unroll
    for(int j=0;j<8;j++){
      int kk = kt*32 + 8*g + j;
      float w = fetchW2(Wx2,Wh2,kk,col);
      short hi = f2bf(w);
      out[j] = (s==0)? hi : f2bf(w - bf2f(hi));
    }
    #pragma unroll
    for(int j=0;j<8;j++) Wpk2[(size_t)t*8+j]=out[j];
  } else if(idx < 14464){
    int i=idx-14336; int g=i>>5,j=i&31;
    Bc1[i]=bx1[g*32+j]+bh1[g*32+j]+b1[g*32+j];
  } else if(idx < 14528){
    int i=idx-14464; int g=i>>4,j=i&15;
    Bc2[i]=bx2[g*16+j]+bh2[g*16+j]+b2g[g*16+j];
  }
}

// ---------- per-timestep ----------
// t=0 only: X slot of Z1 (f32) + Zb1 kt=0 fragments
__global__ void k_init1(const float* __restrict__ xt, float* __restrict__ Z1, short* __restrict__ Zb1){
  int idx=blockIdx.x*256+threadIdx.x;
  if(idx<NN*8){
    int n=idx>>3, c4=idx&7;
    float4 v = ((const float4*)xt)[idx];
    *(float4*)&Z1[(size_t)n*320 + c4*4] = v;
    // fragments: channels 4c4..4c4+3, g=(4c4)>>3, regs (4c4&7)..+3 (aligned 0 or 4)
    unsigned p0 = (unsigned)(unsigned short)f2bf(v.x) | ((unsigned)(unsigned short)f2bf(v.y)<<16);
    unsigned p1 = (unsigned)(unsigned short)f2bf(v.z) | ((unsigned)(unsigned short)f2bf(v.w)<<16);
    size_t fi = fragidx(10, n, c4*4);
    *(unsigned*)&Zb1[fi]   = p0;
    *(unsigned*)&Zb1[fi+2] = p1;
  }
}

// one wave per node; lane handles 2 channels (float2). Writes f32 Z + bf16 fragment shadow Zb.
template<int STRIDE,int NA,int NB,int TK>
__global__ __launch_bounds__(256) void k_spmm(const int* __restrict__ rowptr, const int2* __restrict__ pack,
                       float* __restrict__ Z, short* __restrict__ Zb,
                       int cinA,int coutA,int cppA,int cinB,int coutB,int cppB,
                       float alpha,float beta){
  const int hA=NA/2, hB=NB/2;
  int wlocal = __builtin_amdgcn_readfirstlane(threadIdx.x>>6);
  int wid = blockIdx.x*4 + wlocal;
  if(wid>=NN) return;
  int lane = threadIdx.x&63;
  bool act = lane < hA+hB;
  int cin  = lane<hA ? cinA+2*lane : cinB+2*(lane-hA);
  int cout = lane<hA ? coutA+2*lane : coutB+2*(lane-hA);
  int cpp  = lane<hA ? cppA +2*lane : cppB+2*(lane-hA);
  if(!act) cin=0;
  const float* __restrict__ Zc = Z + cin;
  int e0=rowptr[wid], e1=rowptr[wid+1];
  float accx=0.f, accy=0.f;
  int e=e0;
  for(; e+16<=e1; e+=16){
    float w[16]; float2 z[16];
    #pragma unroll
    for(int j=0;j<16;j++){
      int2 p=pack[e+j];
      w[j]=__int_as_float(p.y);
      z[j]=*(const float2*)&Zc[(unsigned)p.x*STRIDE];
    }
    #pragma unroll
    for(int j=0;j<16;j++){ accx += w[j]*z[j].x; accy += w[j]*z[j].y; }
  }
  for(; e+4<=e1; e+=4){
    float w[4]; float2 z[4];
    #pragma unroll
    for(int j=0;j<4;j++){ int2 p=pack[e+j]; w[j]=__int_as_float(p.y); z[j]=*(const float2*)&Zc[(unsigned)p.x*STRIDE]; }
    #pragma unroll
    for(int j=0;j<4;j++){ accx += w[j]*z[j].x; accy += w[j]*z[j].y; }
  }
  for(; e<e1; ++e){
    int2 p=pack[e];
    float2 z=*(const float2*)&Zc[(unsigned)p.x*STRIDE];
    accx += __int_as_float(p.y)*z.x; accy += __int_as_float(p.y)*z.y;
  }
  if(act){
    float vx = -alpha*accx, vy = -alpha*accy;
    if(beta!=0.f){
      float2 pp=*(const float2*)&Z[(unsigned)wid*STRIDE+cpp];
      vx += beta*pp.x; vy += beta*pp.y;
    }
    *(float2*)&Z[(unsigned)wid*STRIDE+cout]=make_float2(vx,vy);
    unsigned pr = (unsigned)(unsigned short)f2bf(vx) | ((unsigned)(unsigned short)f2bf(vy)<<16);
    *(unsigned*)&Zb[fragidx(TK,wid,cout)] = pr;
  }
}

// G1: A-fragments from Zb1 (pre-packed bf16), W hi+lo split. Fused LSTM layer-1 epilogue.
// 4 waves/block, 1 tile (16 rows) per wave; 157 blocks cover 625 tiles.
__global__ __launch_bounds__(256) void k_gemm1(const short* __restrict__ Zb1, const short* __restrict__ Wpk,
        const float* __restrict__ Bc, const float* __restrict__ wc1,
        float* __restrict__ c1, float* __restrict__ Z1, float* __restrict__ Z2,
        short* __restrict__ Zb1o, short* __restrict__ Zb2){
  int wv=threadIdx.x>>6, lane=threadIdx.x&63;
  int tile=blockIdx.x*4+wv;
  if(tile>=625) return;
  const v8s* Az=(const v8s*)Zb1 + (size_t)tile*640 + lane;
  v8s afr[10];
  #pragma unroll
  for(int kt=0;kt<10;kt++) afr[kt]=Az[kt*64];
  const v8s* Wp=(const v8s*)Wpk;
  v4f acc[8];
  #pragma unroll
  for(int nt=0;nt<8;nt++) acc[nt]=(v4f){0.f,0.f,0.f,0.f};
  #pragma unroll
  for(int kt=0;kt<10;kt++){
    int baseh = kt*1024 + lane;
    #pragma unroll
    for(int nt=0;nt<8;nt++){
      v8s bh = Wp[baseh + nt*64];
      v8s bl = Wp[baseh + 512 + nt*64];
      acc[nt]=__builtin_amdgcn_mfma_f32_16x16x32_bf16(afr[kt],bh,acc[nt],0,0,0);
      acc[nt]=__builtin_amdgcn_mfma_f32_16x16x32_bf16(afr[kt],bl,acc[nt],0,0,0);
    }
  }
  int row0=tile*16;
  int j0=lane&15;
  int r0=row0+(lane>>4)*4;
  #pragma unroll
  for(int reg=0;reg<4;reg++){
    int row=r0+reg;
    #pragma unroll
    for(int jj=0;jj<2;jj++){
      int j=jj*16+j0;
      float c=c1[row*32+j];
      float I =sigmf(acc[0+jj][reg]+Bc[j]      + wc1[j]*c);
      float Fg=sigmf(acc[2+jj][reg]+Bc[32+j]   + wc1[32+j]*c);
      float Ct=tanhf(acc[4+jj][reg]+Bc[64+j]);
      float Cn=Fg*c + I*Ct;
      float O =sigmf(acc[6+jj][reg]+Bc[96+j]   + wc1[64+j]*Cn);
      float h =O*tanhf(Cn);
      short hb=f2bf(h);
      c1[row*32+j]=Cn;
      Z1[(size_t)row*320+160+j]=h;              // next-step L1 H-chain T0 (f32)
      Z2[(size_t)row*240+j]=h;                  // this-step L2 X-chain T0 (f32)
      Zb1o[fragidx(10,row,160+j)]=hb;           // frag shadow
      Zb2 [fragidx(8, row,j)]=hb;
    }
  }
}

// G2: A-fragments from Zb2 (K=256 incl zero pad), fused LSTM layer-2 epilogue + x[t+1] copy.
__global__ __launch_bounds__(256) void k_gemm2(const short* __restrict__ Zb2, const short* __restrict__ Wpk,
        const float* __restrict__ Bc, const float* __restrict__ wc2,
        float* __restrict__ c2, float* __restrict__ h2,
        float* __restrict__ Z2, short* __restrict__ Zb2o,
        const float* __restrict__ xn, float* __restrict__ Z1, short* __restrict__ Zb1){
  int wv=threadIdx.x>>6, lane=threadIdx.x&63;
  int tile=blockIdx.x*4+wv;
  if(tile>=625) return;
  const v8s* Az=(const v8s*)Zb2 + (size_t)tile*512 + lane;
  v8s afr[8];
  #pragma unroll
  for(int kt=0;kt<8;kt++) afr[kt]=Az[kt*64];
  const v8s* Wp=(const v8s*)Wpk;
  v4f acc[4];
  #pragma unroll
  for(int nt=0;nt<4;nt++) acc[nt]=(v4f){0.f,0.f,0.f,0.f};
  #pragma unroll
  for(int kt=0;kt<8;kt++){
    int baseh = kt*512 + lane;
    #pragma unroll
    for(int nt=0;nt<4;nt++){
      v8s bh = Wp[baseh + nt*64];
      v8s bl = Wp[baseh + 256 + nt*64];
      acc[nt]=__builtin_amdgcn_mfma_f32_16x16x32_bf16(afr[kt],bh,acc[nt],0,0,0);
      acc[nt]=__builtin_amdgcn_mfma_f32_16x16x32_bf16(afr[kt],bl,acc[nt],0,0,0);
    }
  }
  int row0=tile*16;
  int j=lane&15;
  int r0=row0+(lane>>4)*4;
  #pragma unroll
  for(int reg=0;reg<4;reg++){
    int row=r0+reg;
    float c=c2[row*16+j];
    float I =sigmf(acc[0][reg]+Bc[j]    +wc2[j]*c);
    float Fg=sigmf(acc[1][reg]+Bc[16+j] +wc2[16+j]*c);
    float Ct=tanhf(acc[2][reg]+Bc[32+j]);
    float Cn=Fg*c+I*Ct;
    float O =sigmf(acc[3][reg]+Bc[48+j] +wc2[32+j]*Cn);
    float h =O*tanhf(Cn);
    c2[row*16+j]=Cn; h2[row*16+j]=h;
    Z2[(size_t)row*240+160+j]=h;               // next-step L2 H-chain T0 (f32)
    Zb2o[fragidx(8,row,160+j)]=f2bf(h);        // frag shadow
    if(xn){
      float2 xv=*(const float2*)&xn[(size_t)row*32+j*2];
      *(float2*)&Z1[(size_t)row*320+j*2]=xv;   // next-step L1 X-chain T0 (f32)
      unsigned pr=(unsigned)(unsigned short)f2bf(xv.x) | ((unsigned)(unsigned short)f2bf(xv.y)<<16);
      *(unsigned*)&Zb1[fragidx(10,row,2*j)]=pr;
    }
  }
}

// ---------- readout ----------
__global__ void k_pool(const float* __restrict__ h2, const int* __restrict__ batch, float* __restrict__ u){
  int idx=blockIdx.x*256+threadIdx.x;
  if(idx<NN*16){
    int n=idx>>4, j=idx&15;
    atomicAdd(&u[batch[n]*16+j], h2[idx]);
  }
}

__global__ void k_final(const float* __restrict__ u, const float* __restrict__ lw, const float* __restrict__ lb,
                        float* __restrict__ out){
  int g=threadIdx.x;
  if(g<NG){
    float s=lb[0];
    #pragma unroll
    for(int j=0;j<16;j++) s += u[g*16+j]*lw[j];
    out[g]=s;
  }
}

extern "C" void kernel_launch(void* const* d_in, const int* in_sizes, int n_in,
                              void* d_out, int out_size, void* d_ws, size_t ws_size,
                              hipStream_t stream){
  const float* x   = (const float*)d_in[0];
  const int*   ei  = (const int*)d_in[1];
  const float* ea  = (const float*)d_in[2];
  const int*   bat = (const int*)d_in[3];
  const float* Wx1=(const float*)d_in[4];  const float* bx1=(const float*)d_in[5];
  const float* Wh1=(const float*)d_in[6];  const float* bh1=(const float*)d_in[7];
  const float* wc1=(const float*)d_in[8];  const float* b1 =(const float*)d_in[9];
  const float* Wx2=(const float*)d_in[10]; const float* bx2=(const float*)d_in[11];
  const float* Wh2=(const float*)d_in[12]; const float* bh2=(const float*)d_in[13];
  const float* wc2=(const float*)d_in[14]; const float* b2 =(const float*)d_in[15];
  const float* lw =(const float*)d_in[16]; const float* lb =(const float*)d_in[17];
  const int* src = ei; const int* dst = ei+EE;

  float* ws = (float*)d_ws;
  size_t off=0;
  auto alloc=[&](size_t n)->float*{ float* p=ws+off; off+=(n+15)&~(size_t)15; return p; };
  // zeroed region: deg, c1, c2, u, cnt, Z1, Z2(+pad), Zb1, Zb2
  float* deg=alloc(NN);
  float* c1=alloc((size_t)NN*32);
  float* c2=alloc((size_t)NN*16);
  float* u =alloc(NG*16);
  int*   cnt=(int*)alloc(NN);
  float* Z1=alloc((size_t)NN*320);
  float* Z2=alloc((size_t)NN*240+80);
  short* Zb1=(short*)alloc(625*10*64*8/2);   // 3.2M shorts = 1.6M floats
  short* Zb2=(short*)alloc(625*8*64*8/2);
  size_t zeroEnd=off;
  float* h2=alloc((size_t)NN*16);
  float* dis=alloc(NN);
  float* wnorm=alloc(EE);
  int*   rowptr=(int*)alloc(NN+1);
  int*   wp=(int*)alloc(NN);
  int2*  pack=(int2*)alloc((size_t)EE*2);
  short* Wpk1=(short*)alloc(10240*4);
  short* Wpk2=(short*)alloc(4096*4);
  float* Bc1=alloc(128);     float* Bc2=alloc(64);
  (void)ws_size; (void)in_sizes; (void)n_in; (void)out_size;

  hipMemsetAsync(d_ws, 0, zeroEnd*sizeof(float), stream);
  k_deg    <<<1250,256,0,stream>>>(src,ea,deg);
  k_dis    <<<40,256,0,stream>>>(deg,dis);
  k_wnorm  <<<1250,256,0,stream>>>(src,dst,ea,dis,wnorm,cnt);
  k_scan   <<<1,1024,0,stream>>>(cnt,rowptr,wp);
  k_scatter<<<1250,256,0,stream>>>(src,dst,wnorm,wp,pack);
  k_wreorg <<<57,256,0,stream>>>(Wx1,bx1,Wh1,bh1,b1,Wx2,bx2,Wh2,bh2,b2,Wpk1,Wpk2,Bc1,Bc2);

  k_init1<<<313,256,0,stream>>>(x, Z1, Zb1);
  for(int t=0;t<TT;t++){
    for(int k=1;k<5;k++){
      float alpha = (k==1)?1.f:2.f, beta = (k==1)?0.f:-1.f;
      k_spmm<320,32,32,10><<<2500,256,0,stream>>>(rowptr,pack,Z1,Zb1,
          (k-1)*32, k*32, (k-2)*32,
          160+(k-1)*32, 160+k*32, 160+(k-2)*32, alpha,beta);
    }
    k_gemm1<<<157,256,0,stream>>>(Zb1,Wpk1,Bc1,wc1,c1,Z1,Z2,Zb1,Zb2);
    for(int k=1;k<5;k++){
      float alpha = (k==1)?1.f:2.f, beta = (k==1)?0.f:-1.f;
      k_spmm<240,32,16,8><<<2500,256,0,stream>>>(rowptr,pack,Z2,Zb2,
          (k-1)*32, k*32, (k-2)*32,
          160+(k-1)*16, 160+k*16, 160+(k-2)*16, alpha,beta);
    }
    k_gemm2<<<157,256,0,stream>>>(Zb2,Wpk2,Bc2,wc2,c2,h2,Z2,Zb2,
          (t<TT-1)? x+(size_t)(t+1)*NN*32 : nullptr, Z1, Zb1);
  }
  k_pool <<<625,256,0,stream>>>(h2,bat,u);
  k_final<<<1,64,0,stream>>>(u,lw,lb,(float*)d_out);
}

// Round 8
// 924.469 us; speedup vs baseline: 12.4366x; 1.3980x over previous
//
#include <hip/hip_runtime.h>
#include <hip/hip_bf16.h>

#define TT 8
#define NN 10000
#define EE 320000
#define NG 64
#define SZS 400   // ZS row stride (f32): [0..160) h1 T0..4 | [160..240) h2 T0..4 | [240..400) x T0..4

typedef short v8s __attribute__((ext_vector_type(8)));
typedef float v4f __attribute__((ext_vector_type(4)));

__device__ __forceinline__ float sigmf(float x){ return 1.f/(1.f+expf(-x)); }
__device__ __forceinline__ short f2bf(float f){
  unsigned u=__float_as_uint(f);
  unsigned r=(u + 0x7FFFu + ((u>>16)&1u))>>16;
  return (short)r;
}
__device__ __forceinline__ float bf2f(short s){
  return __uint_as_float(((unsigned)(unsigned short)s)<<16);
}
// fragment index: Zb[((tile*TK+kt)*64 + g*16 + m)*8 + reg], c = kt*32 + 8g + reg, m = row&15
__device__ __forceinline__ size_t fragidx(int TK,int row,int c){
  int tile=row>>4, m=row&15, kt=c>>5, cc=c&31;
  return ((size_t)(tile*TK+kt)*64 + (cc>>3)*16 + m)*8 + (cc&7);
}

// ---------- setup ----------
__global__ void k_deg(const int* __restrict__ src, const float* __restrict__ ea, float* __restrict__ deg){
  int e = blockIdx.x*256 + threadIdx.x;
  if(e<EE) atomicAdd(&deg[src[e]], ea[e]);
}

__global__ void k_dis(const float* __restrict__ deg, float* __restrict__ dis){
  int n = blockIdx.x*256+threadIdx.x;
  if(n<NN){ float d=deg[n]; dis[n] = d>0.f ? rsqrtf(d) : 0.f; }
}

__global__ void k_wnorm(const int* __restrict__ src, const int* __restrict__ dst, const float* __restrict__ ea,
                        const float* __restrict__ dis, float* __restrict__ wnorm, int* __restrict__ cnt){
  int e = blockIdx.x*256+threadIdx.x;
  if(e<EE){
    int s=src[e], d=dst[e];
    wnorm[e] = dis[s]*ea[e]*dis[d];
    atomicAdd(&cnt[d],1);
  }
}

__global__ __launch_bounds__(1024) void k_scan(const int* __restrict__ cnt, int* __restrict__ rowptr, int* __restrict__ wp){
  __shared__ int wsum[16];
  __shared__ int carrysh;
  int tid=threadIdx.x, lane=tid&63, wv=tid>>6;
  if(tid==0){ carrysh=0; rowptr[0]=0; }
  __syncthreads();
  for(int base=0;base<NN;base+=1024){
    int i=base+tid;
    int v=(i<NN)?cnt[i]:0;
    int s=v;
    #pragma unroll
    for(int d=1;d<64;d<<=1){ int t=__shfl_up(s,d,64); if(lane>=d) s+=t; }
    if(lane==63) wsum[wv]=s;
    __syncthreads();
    if(wv==0 && lane<16){
      int t=wsum[lane]; int ss=t;
      #pragma unroll
      for(int d=1;d<16;d<<=1){ int u=__shfl_up(ss,d,64); if(lane>=d) ss+=u; }
      wsum[lane]=ss-t;
    }
    __syncthreads();
    int total = carrysh + wsum[wv] + s;
    if(i<NN) rowptr[i+1]=total;
    __syncthreads();
    if(tid==1023) carrysh = total;
    __syncthreads();
  }
  for(int i=tid;i<NN;i+=1024) wp[i]=rowptr[i];
}

__global__ void k_scatter(const int* __restrict__ src, const int* __restrict__ dst, const float* __restrict__ wnorm,
                          int* __restrict__ wp, int2* __restrict__ pack){
  int e = blockIdx.x*256+threadIdx.x;
  if(e<EE){
    int d=dst[e];
    int pos = atomicAdd(&wp[d],1);
    pack[pos] = make_int2(src[e], __float_as_int(wnorm[e]));
  }
}

// fetch original combined-K weights
__device__ __forceinline__ float fetchW1(const float* Wx, const float* Wh, int kk, int col){
  int g=col>>5, j=col&31;
  if(kk<160){ int k=kk>>5, i=kk&31; return Wx[((g*5+k)*32+i)*32+j]; }
  int rr=kk-160; int k=rr>>5, i=rr&31; return Wh[((g*5+k)*32+i)*32+j];
}
__device__ __forceinline__ float fetchW2(const float* Wx, const float* Wh, int kk, int col){
  int g=col>>4, j=col&15;
  if(kk<160){ int k=kk>>5, i=kk&31; return Wx[((g*5+k)*32+i)*16+j]; }
  if(kk<240){ int rr=kk-160; int k=rr>>4, i=rr&15; return Wh[((g*5+k)*16+i)*16+j]; }
  return 0.f;
}

// Pack W into MFMA B-fragments with k-map phi(kt,g,reg) = kt*32 + 8*g + reg.
__global__ void k_wreorg(const float* __restrict__ Wx1,const float* __restrict__ bx1,
                         const float* __restrict__ Wh1,const float* __restrict__ bh1,const float* __restrict__ b1,
                         const float* __restrict__ Wx2,const float* __restrict__ bx2,
                         const float* __restrict__ Wh2,const float* __restrict__ bh2,const float* __restrict__ b2g,
                         short* __restrict__ Wpk1, short* __restrict__ Wpk2,
                         float* __restrict__ Bc1,float* __restrict__ Bc2){
  int idx = blockIdx.x*256+threadIdx.x;
  if(idx < 10240){
    int lane=idx&63, rest=idx>>6;
    int nt=rest&7, s=(rest>>3)&1, kt=rest>>4;
    int col = nt*16 + (lane&15);
    int g = lane>>4;
    short out[8];
    #pragma unroll
    for(int j=0;j<8;j++){
      int kk = kt*32 + 8*g + j;
      float w = fetchW1(Wx1,Wh1,kk,col);
      short hi = f2bf(w);
      out[j] = (s==0)? hi : f2bf(w - bf2f(hi));
    }
    #pragma unroll
    for(int j=0;j<8;j++) Wpk1[(size_t)idx*8+j]=out[j];
  } else if(idx < 14336){
    int t=idx-10240;
    int lane=t&63, rest=t>>6;
    int nt=rest&3, s=(rest>>2)&1, kt=rest>>3;
    int col = nt*16 + (lane&15);
    int g = lane>>4;
    short out[8];
    #pragma unroll
    for(int j=0;j<8;j++){
      int kk = kt*32 + 8*g + j;
      float w = fetchW2(Wx2,Wh2,kk,col);
      short hi = f2bf(w);
      out[j] = (s==0)? hi : f2bf(w - bf2f(hi));
    }
    #pragma unroll
    for(int j=0;j<8;j++) Wpk2[(size_t)t*8+j]=out[j];
  } else if(idx < 14464){
    int i=idx-14336; int g=i>>5,j=i&31;
    Bc1[i]=bx1[g*32+j]+bh1[g*32+j]+b1[g*32+j];
  } else if(idx < 14528){
    int i=idx-14464; int g=i>>4,j=i&15;
    Bc2[i]=bx2[g*16+j]+bh2[g*16+j]+b2g[g*16+j];
  }
}

// ---------- per-timestep ----------
// t=0 only: x(0) -> ZS x-T0 slot + Zb1 kt0 fragments
__global__ void k_init1(const float* __restrict__ xt, float* __restrict__ ZS, short* __restrict__ Zb1){
  int idx=blockIdx.x*256+threadIdx.x;
  if(idx<NN*8){
    int n=idx>>3, c4=idx&7;
    float4 v = ((const float4*)xt)[idx];
    *(float4*)&ZS[(size_t)n*SZS + 240 + c4*4] = v;
    unsigned p0 = (unsigned)(unsigned short)f2bf(v.x) | ((unsigned)(unsigned short)f2bf(v.y)<<16);
    unsigned p1 = (unsigned)(unsigned short)f2bf(v.z) | ((unsigned)(unsigned short)f2bf(v.w)<<16);
    size_t fi = fragidx(5, n, c4*4);
    *(unsigned*)&Zb1[fi]   = p0;
    *(unsigned*)&Zb1[fi+2] = p1;
  }
}

// One wave per node; lane handles 2 channels (float2) of one chain.
// MODE 0 = x-only (pre-loop): 16 lanes. MODE 1 = full (h1,h2,x): 40 lanes. MODE 2 = no-x (last step): 24 lanes.
template<int MODE>
__global__ __launch_bounds__(256) void k_spmm(const int* __restrict__ rowptr, const int2* __restrict__ pack,
    float* __restrict__ ZS, short* __restrict__ Zb1, short* __restrict__ Zb2, int k){
  const int NACT = (MODE==0)?16 : (MODE==1)?40 : 24;
  int wlocal = __builtin_amdgcn_readfirstlane(threadIdx.x>>6);
  int wid = blockIdx.x*4 + wlocal;
  if(wid>=NN) return;
  int l = threadIdx.x&63;
  int cb, w, lb;
  if(MODE==0){ cb=240; w=32; lb=0; }
  else if(l<16){ cb=0; w=32; lb=0; }
  else if(l<24){ cb=160; w=16; lb=16; }
  else { cb=240; w=32; lb=24; }
  bool act = l < NACT;
  int o = 2*(l-lb);
  int cin  = cb + (k-1)*w + o;
  int cout = cb + k*w + o;
  int cpp  = cb + (k-2)*w + o;
  if(!act) cin = (MODE==0?240:0) + (k-1)*32;   // clamp into an active (already-fetched) region
  const float* __restrict__ Zc = ZS + cin;
  int e0=rowptr[wid], e1=rowptr[wid+1];
  float accx=0.f, accy=0.f;
  int e=e0;
  for(; e+16<=e1; e+=16){
    float wgt[16]; float2 z[16];
    #pragma unroll
    for(int j=0;j<16;j++){
      int2 p=pack[e+j];
      wgt[j]=__int_as_float(p.y);
      z[j]=*(const float2*)&Zc[(unsigned)p.x*SZS];
    }
    #pragma unroll
    for(int j=0;j<16;j++){ accx += wgt[j]*z[j].x; accy += wgt[j]*z[j].y; }
  }
  for(; e+4<=e1; e+=4){
    float wgt[4]; float2 z[4];
    #pragma unroll
    for(int j=0;j<4;j++){ int2 p=pack[e+j]; wgt[j]=__int_as_float(p.y); z[j]=*(const float2*)&Zc[(unsigned)p.x*SZS]; }
    #pragma unroll
    for(int j=0;j<4;j++){ accx += wgt[j]*z[j].x; accy += wgt[j]*z[j].y; }
  }
  for(; e<e1; ++e){
    int2 p=pack[e];
    float2 z=*(const float2*)&Zc[(unsigned)p.x*SZS];
    accx += __int_as_float(p.y)*z.x; accy += __int_as_float(p.y)*z.y;
  }
  if(act){
    float alpha=(k==1)?1.f:2.f;
    float vx = -alpha*accx, vy = -alpha*accy;
    if(k>=2){
      float2 pp=*(const float2*)&ZS[(unsigned)wid*SZS+cpp];
      vx -= pp.x; vy -= pp.y;
    }
    *(float2*)&ZS[(unsigned)wid*SZS+cout]=make_float2(vx,vy);
    unsigned pr = (unsigned)(unsigned short)f2bf(vx) | ((unsigned)(unsigned short)f2bf(vy)<<16);
    if(MODE!=0 && l<24) *(unsigned*)&Zb2[fragidx(8,wid,cout)] = pr;
    else                *(unsigned*)&Zb1[fragidx(5,wid,cout-240)] = pr;
  }
}

// G1: A = [T(x(t)) (Zb1 kt0..4) | T(h1(t-1)) (Zb2 kt0..4)], K=320. Fused LSTM layer-1 epilogue.
// Writes h1 -> ZS h1-T0 + Zb2 kt0; x(t+1) -> ZS x-T0 + Zb1 kt0.
__global__ __launch_bounds__(256) void k_gemm1(const short* Zb1r, const short* Zb2r, const short* __restrict__ Wpk,
        const float* __restrict__ Bc, const float* __restrict__ wc1,
        float* __restrict__ c1, float* __restrict__ ZS,
        short* Zb1w, short* Zb2w, const float* __restrict__ xn){
  int wv=threadIdx.x>>6, lane=threadIdx.x&63;
  int tile=blockIdx.x*4+wv;
  if(tile>=625) return;
  const v8s* A1=(const v8s*)Zb1r + (size_t)tile*320 + lane;
  const v8s* A2=(const v8s*)Zb2r + (size_t)tile*512 + lane;
  v8s afr[10];
  #pragma unroll
  for(int kt=0;kt<5;kt++){ afr[kt]=A1[kt*64]; afr[5+kt]=A2[kt*64]; }
  const v8s* Wp=(const v8s*)Wpk;
  v4f acc[8];
  #pragma unroll
  for(int nt=0;nt<8;nt++) acc[nt]=(v4f){0.f,0.f,0.f,0.f};
  #pragma unroll
  for(int kt=0;kt<10;kt++){
    int baseh = kt*1024 + lane;
    #pragma unroll
    for(int nt=0;nt<8;nt++){
      v8s bh = Wp[baseh + nt*64];
      v8s bl = Wp[baseh + 512 + nt*64];
      acc[nt]=__builtin_amdgcn_mfma_f32_16x16x32_bf16(afr[kt],bh,acc[nt],0,0,0);
      acc[nt]=__builtin_amdgcn_mfma_f32_16x16x32_bf16(afr[kt],bl,acc[nt],0,0,0);
    }
  }
  int row0=tile*16;
  int j0=lane&15;
  int r0=row0+(lane>>4)*4;
  #pragma unroll
  for(int reg=0;reg<4;reg++){
    int row=r0+reg;
    #pragma unroll
    for(int jj=0;jj<2;jj++){
      int j=jj*16+j0;
      float c=c1[row*32+j];
      float I =sigmf(acc[0+jj][reg]+Bc[j]      + wc1[j]*c);
      float Fg=sigmf(acc[2+jj][reg]+Bc[32+j]   + wc1[32+j]*c);
      float Ct=tanhf(acc[4+jj][reg]+Bc[64+j]);
      float Cn=Fg*c + I*Ct;
      float O =sigmf(acc[6+jj][reg]+Bc[96+j]   + wc1[64+j]*Cn);
      float h =O*tanhf(Cn);
      c1[row*32+j]=Cn;
      ZS[(size_t)row*SZS + j]=h;               // h1 T0 (f32)
      Zb2w[fragidx(8,row,j)]=f2bf(h);          // h1 T0 fragment (gemm2 A / next gemm1 H-part source chain)
    }
    if(xn){
      float2 xv=*(const float2*)&xn[(size_t)row*32 + 2*j0];
      *(float2*)&ZS[(size_t)row*SZS + 240 + 2*j0]=xv;   // x(t+1) T0 (f32)
      unsigned pr=(unsigned)(unsigned short)f2bf(xv.x) | ((unsigned)(unsigned short)f2bf(xv.y)<<16);
      *(unsigned*)&Zb1w[fragidx(5,row,2*j0)]=pr;
    }
  }
}

// G2: A = Zb2 kt0..7 = [T(h1(t)) | T(h2(t-1)) | pad], K=256. Fused LSTM layer-2 epilogue.
__global__ __launch_bounds__(256) void k_gemm2(const short* Zb2r, const short* __restrict__ Wpk,
        const float* __restrict__ Bc, const float* __restrict__ wc2,
        float* __restrict__ c2, float* __restrict__ h2,
        float* __restrict__ ZS, short* Zb2w){
  int wv=threadIdx.x>>6, lane=threadIdx.x&63;
  int tile=blockIdx.x*4+wv;
  if(tile>=625) return;
  const v8s* Az=(const v8s*)Zb2r + (size_t)tile*512 + lane;
  v8s afr[8];
  #pragma unroll
  for(int kt=0;kt<8;kt++) afr[kt]=Az[kt*64];
  const v8s* Wp=(const v8s*)Wpk;
  v4f acc[4];
  #pragma unroll
  for(int nt=0;nt<4;nt++) acc[nt]=(v4f){0.f,0.f,0.f,0.f};
  #pragma unroll
  for(int kt=0;kt<8;kt++){
    int baseh = kt*512 + lane;
    #pragma unroll
    for(int nt=0;nt<4;nt++){
      v8s bh = Wp[baseh + nt*64];
      v8s bl = Wp[baseh + 256 + nt*64];
      acc[nt]=__builtin_amdgcn_mfma_f32_16x16x32_bf16(afr[kt],bh,acc[nt],0,0,0);
      acc[nt]=__builtin_amdgcn_mfma_f32_16x16x32_bf16(afr[kt],bl,acc[nt],0,0,0);
    }
  }
  int row0=tile*16;
  int j=lane&15;
  int r0=row0+(lane>>4)*4;
  #pragma unroll
  for(int reg=0;reg<4;reg++){
    int row=r0+reg;
    float c=c2[row*16+j];
    float I =sigmf(acc[0][reg]+Bc[j]    +wc2[j]*c);
    float Fg=sigmf(acc[1][reg]+Bc[16+j] +wc2[16+j]*c);
    float Ct=tanhf(acc[2][reg]+Bc[32+j]);
    float Cn=Fg*c+I*Ct;
    float O =sigmf(acc[3][reg]+Bc[48+j] +wc2[32+j]*Cn);
    float h =O*tanhf(Cn);
    c2[row*16+j]=Cn; h2[row*16+j]=h;
    ZS[(size_t)row*SZS + 160 + j]=h;            // h2 T0 (f32)
    Zb2w[fragidx(8,row,160+j)]=f2bf(h);         // h2 T0 fragment
  }
}

// ---------- readout ----------
__global__ void k_pool(const float* __restrict__ h2, const int* __restrict__ batch, float* __restrict__ u){
  int idx=blockIdx.x*256+threadIdx.x;
  if(idx<NN*16){
    int n=idx>>4, j=idx&15;
    atomicAdd(&u[batch[n]*16+j], h2[idx]);
  }
}

__global__ void k_final(const float* __restrict__ u, const float* __restrict__ lw, const float* __restrict__ lb,
                        float* __restrict__ out){
  int g=threadIdx.x;
  if(g<NG){
    float s=lb[0];
    #pragma unroll
    for(int j=0;j<16;j++) s += u[g*16+j]*lw[j];
    out[g]=s;
  }
}

extern "C" void kernel_launch(void* const* d_in, const int* in_sizes, int n_in,
                              void* d_out, int out_size, void* d_ws, size_t ws_size,
                              hipStream_t stream){
  const float* x   = (const float*)d_in[0];
  const int*   ei  = (const int*)d_in[1];
  const float* ea  = (const float*)d_in[2];
  const int*   bat = (const int*)d_in[3];
  const float* Wx1=(const float*)d_in[4];  const float* bx1=(const float*)d_in[5];
  const float* Wh1=(const float*)d_in[6];  const float* bh1=(const float*)d_in[7];
  const float* wc1=(const float*)d_in[8];  const float* b1 =(const float*)d_in[9];
  const float* Wx2=(const float*)d_in[10]; const float* bx2=(const float*)d_in[11];
  const float* Wh2=(const float*)d_in[12]; const float* bh2=(const float*)d_in[13];
  const float* wc2=(const float*)d_in[14]; const float* b2 =(const float*)d_in[15];
  const float* lw =(const float*)d_in[16]; const float* lb =(const float*)d_in[17];
  const int* src = ei; const int* dst = ei+EE;

  float* ws = (float*)d_ws;
  size_t off=0;
  auto alloc=[&](size_t n)->float*{ float* p=ws+off; off+=(n+15)&~(size_t)15; return p; };
  // zeroed region: deg, c1, c2, u, cnt, ZS, Zb1, Zb2
  float* deg=alloc(NN);
  float* c1=alloc((size_t)NN*32);
  float* c2=alloc((size_t)NN*16);
  float* u =alloc(NG*16);
  int*   cnt=(int*)alloc(NN);
  float* ZS=alloc((size_t)NN*SZS);
  short* Zb1=(short*)alloc(625*5*64*8/2);    // 1.6M shorts
  short* Zb2=(short*)alloc(625*8*64*8/2);    // 2.56M shorts
  size_t zeroEnd=off;
  float* h2=alloc((size_t)NN*16);
  float* dis=alloc(NN);
  float* wnorm=alloc(EE);
  int*   rowptr=(int*)alloc(NN+1);
  int*   wp=(int*)alloc(NN);
  int2*  pack=(int2*)alloc((size_t)EE*2);
  short* Wpk1=(short*)alloc(10240*4);
  short* Wpk2=(short*)alloc(4096*4);
  float* Bc1=alloc(128);     float* Bc2=alloc(64);
  (void)ws_size; (void)in_sizes; (void)n_in; (void)out_size;

  hipMemsetAsync(d_ws, 0, zeroEnd*sizeof(float), stream);
  k_deg    <<<1250,256,0,stream>>>(src,ea,deg);
  k_dis    <<<40,256,0,stream>>>(deg,dis);
  k_wnorm  <<<1250,256,0,stream>>>(src,dst,ea,dis,wnorm,cnt);
  k_scan   <<<1,1024,0,stream>>>(cnt,rowptr,wp);
  k_scatter<<<1250,256,0,stream>>>(src,dst,wnorm,wp,pack);
  k_wreorg <<<57,256,0,stream>>>(Wx1,bx1,Wh1,bh1,b1,Wx2,bx2,Wh2,bh2,b2,Wpk1,Wpk2,Bc1,Bc2);

  k_init1<<<313,256,0,stream>>>(x, ZS, Zb1);
  for(int k=1;k<5;k++)
    k_spmm<0><<<2500,256,0,stream>>>(rowptr,pack,ZS,Zb1,Zb2,k);   // T_k(x(0))

  for(int t=0;t<TT;t++){
    k_gemm1<<<157,256,0,stream>>>(Zb1,Zb2,Wpk1,Bc1,wc1,c1,ZS,Zb1,Zb2,
          (t<TT-1)? x+(size_t)(t+1)*NN*32 : nullptr);
    if(t<TT-1){
      for(int k=1;k<5;k++)
        k_spmm<1><<<2500,256,0,stream>>>(rowptr,pack,ZS,Zb1,Zb2,k);  // T_k(h1(t)), T_k(h2(t-1)), T_k(x(t+1))
    } else {
      for(int k=1;k<5;k++)
        k_spmm<2><<<2500,256,0,stream>>>(rowptr,pack,ZS,Zb1,Zb2,k);  // no x-chain on last step
    }
    k_gemm2<<<157,256,0,stream>>>(Zb2,Wpk2,Bc2,wc2,c2,h2,ZS,Zb2);
  }
  k_pool <<<625,256,0,stream>>>(h2,bat,u);
  k_final<<<1,64,0,stream>>>(u,lw,lb,(float*)d_out);
}

// Round 9
// 661.531 us; speedup vs baseline: 17.3797x; 1.3975x over previous
//
#include <hip/hip_runtime.h>
#include <hip/hip_bf16.h>

#define TT 8
#define NN 10000
#define EE 320000
#define NG 64
#define SZS 400   // ZS f32 row: [0..160) h1 T0..4 | [160..240) h2 T0..4 | [240..400) x T0..4
#define SZH 384   // ZH fp16 row: 4 levels x 96 (h1[0,32) h2[32,48) x[48,80) pad[80,96))

typedef short v8s __attribute__((ext_vector_type(8)));
typedef _Float16 v8h __attribute__((ext_vector_type(8)));
typedef float v4f __attribute__((ext_vector_type(4)));

__device__ __forceinline__ float sigmf(float x){ return 1.f/(1.f+expf(-x)); }
__device__ __forceinline__ unsigned short f2h(float f){ _Float16 h=(_Float16)f; return __builtin_bit_cast(unsigned short,h); }
__device__ __forceinline__ float h2f(unsigned short s){ return (float)__builtin_bit_cast(_Float16,s); }
__device__ __forceinline__ unsigned pack2h(float x,float y){ return (unsigned)f2h(x) | ((unsigned)f2h(y)<<16); }
// fragment index: c = kt*32 + 8g + reg, m = row&15
__device__ __forceinline__ size_t fragidx(int TK,int row,int c){
  int tile=row>>4, m=row&15, kt=c>>5, cc=c&31;
  return ((size_t)(tile*TK+kt)*64 + (cc>>3)*16 + m)*8 + (cc&7);
}

// ---------- setup ----------
__global__ void k_deg(const int* __restrict__ src, const float* __restrict__ ea, float* __restrict__ deg){
  int e = blockIdx.x*256 + threadIdx.x;
  if(e<EE) atomicAdd(&deg[src[e]], ea[e]);
}

__global__ void k_dis(const float* __restrict__ deg, float* __restrict__ dis){
  int n = blockIdx.x*256+threadIdx.x;
  if(n<NN){ float d=deg[n]; dis[n] = d>0.f ? rsqrtf(d) : 0.f; }
}

__global__ void k_wnorm(const int* __restrict__ src, const int* __restrict__ dst, const float* __restrict__ ea,
                        const float* __restrict__ dis, float* __restrict__ wnorm, int* __restrict__ cnt){
  int e = blockIdx.x*256+threadIdx.x;
  if(e<EE){
    int s=src[e], d=dst[e];
    wnorm[e] = dis[s]*ea[e]*dis[d];
    atomicAdd(&cnt[d],1);
  }
}

__global__ __launch_bounds__(1024) void k_scan(const int* __restrict__ cnt, int* __restrict__ rowptr, int* __restrict__ wp){
  __shared__ int wsum[16];
  __shared__ int carrysh;
  int tid=threadIdx.x, lane=tid&63, wv=tid>>6;
  if(tid==0){ carrysh=0; rowptr[0]=0; }
  __syncthreads();
  for(int base=0;base<NN;base+=1024){
    int i=base+tid;
    int v=(i<NN)?cnt[i]:0;
    int s=v;
    #pragma unroll
    for(int d=1;d<64;d<<=1){ int t=__shfl_up(s,d,64); if(lane>=d) s+=t; }
    if(lane==63) wsum[wv]=s;
    __syncthreads();
    if(wv==0 && lane<16){
      int t=wsum[lane]; int ss=t;
      #pragma unroll
      for(int d=1;d<16;d<<=1){ int u=__shfl_up(ss,d,64); if(lane>=d) ss+=u; }
      wsum[lane]=ss-t;
    }
    __syncthreads();
    int total = carrysh + wsum[wv] + s;
    if(i<NN) rowptr[i+1]=total;
    __syncthreads();
    if(tid==1023) carrysh = total;
    __syncthreads();
  }
  for(int i=tid;i<NN;i+=1024) wp[i]=rowptr[i];
}

__global__ void k_scatter(const int* __restrict__ src, const int* __restrict__ dst, const float* __restrict__ wnorm,
                          int* __restrict__ wp, int2* __restrict__ pack){
  int e = blockIdx.x*256+threadIdx.x;
  if(e<EE){
    int d=dst[e];
    int pos = atomicAdd(&wp[d],1);
    pack[pos] = make_int2(src[e], __float_as_int(wnorm[e]));
  }
}

// fetch original combined-K weights
__device__ __forceinline__ float fetchW1(const float* Wx, const float* Wh, int kk, int col){
  int g=col>>5, j=col&31;
  if(kk<160){ int k=kk>>5, i=kk&31; return Wx[((g*5+k)*32+i)*32+j]; }
  int rr=kk-160; int k=rr>>5, i=rr&31; return Wh[((g*5+k)*32+i)*32+j];
}
__device__ __forceinline__ float fetchW2(const float* Wx, const float* Wh, int kk, int col){
  int g=col>>4, j=col&15;
  if(kk<160){ int k=kk>>5, i=kk&31; return Wx[((g*5+k)*32+i)*16+j]; }
  if(kk<240){ int rr=kk-160; int k=rr>>4, i=rr&15; return Wh[((g*5+k)*16+i)*16+j]; }
  return 0.f;
}

// Pack W into fp16 MFMA B-fragments, k-map phi(kt,g,reg)=kt*32+8g+reg.
// Wpk1: [kt(10)][nt(8)][lane(64)] x 8 fp16 ; Wpk2: [kt(8)][nt(4)][lane(64)] x 8 fp16
__global__ void k_wreorg(const float* __restrict__ Wx1,const float* __restrict__ bx1,
                         const float* __restrict__ Wh1,const float* __restrict__ bh1,const float* __restrict__ b1,
                         const float* __restrict__ Wx2,const float* __restrict__ bx2,
                         const float* __restrict__ Wh2,const float* __restrict__ bh2,const float* __restrict__ b2g,
                         short* __restrict__ Wpk1, short* __restrict__ Wpk2,
                         float* __restrict__ Bc1,float* __restrict__ Bc2){
  int idx = blockIdx.x*256+threadIdx.x;
  if(idx < 5120){
    int lane=idx&63, rest=idx>>6;
    int nt=rest&7, kt=rest>>3;
    int col = nt*16 + (lane&15);
    int g = lane>>4;
    #pragma unroll
    for(int j=0;j<8;j++){
      int kk = kt*32 + 8*g + j;
      Wpk1[(size_t)idx*8+j]=(short)f2h(fetchW1(Wx1,Wh1,kk,col));
    }
  } else if(idx < 7168){
    int t=idx-5120;
    int lane=t&63, rest=t>>6;
    int nt=rest&3, kt=rest>>2;
    int col = nt*16 + (lane&15);
    int g = lane>>4;
    #pragma unroll
    for(int j=0;j<8;j++){
      int kk = kt*32 + 8*g + j;
      Wpk2[(size_t)t*8+j]=(short)f2h(fetchW2(Wx2,Wh2,kk,col));
    }
  } else if(idx < 7296){
    int i=idx-7168; int g=i>>5,j=i&31;
    Bc1[i]=bx1[g*32+j]+bh1[g*32+j]+b1[g*32+j];
  } else if(idx < 7360){
    int i=idx-7296; int g=i>>4,j=i&15;
    Bc2[i]=bx2[g*16+j]+bh2[g*16+j]+b2g[g*16+j];
  }
}

// ---------- per-timestep ----------
// t=0 only: x(0) -> ZS x-T0 + ZH level0 x-part + Zb1 kt0
__global__ void k_init1(const float* __restrict__ xt, float* __restrict__ ZS,
                        unsigned short* __restrict__ ZH, short* __restrict__ Zb1){
  int idx=blockIdx.x*256+threadIdx.x;
  if(idx<NN*8){
    int n=idx>>3, c4=idx&7;
    float4 v = ((const float4*)xt)[idx];
    *(float4*)&ZS[(size_t)n*SZS + 240 + c4*4] = v;
    unsigned p0=pack2h(v.x,v.y), p1=pack2h(v.z,v.w);
    *(unsigned*)&ZH[(size_t)n*SZH + 48 + c4*4]     = p0;
    *(unsigned*)&ZH[(size_t)n*SZH + 48 + c4*4 + 2] = p1;
    size_t fi = fragidx(5, n, c4*4);
    *(unsigned*)&Zb1[fi]   = p0;
    *(unsigned*)&Zb1[fi+2] = p1;
  }
}

// One wave per node; lane handles 2 channels. Gathers fp16 from ZH (3 lines/edge).
// MODE 0 = x-only (pre-loop, 16 lanes). MODE 1 = h1,h2,x (40 lanes). MODE 2 = h1,h2 (24 lanes).
template<int MODE>
__global__ __launch_bounds__(256) void k_spmm(const int* __restrict__ rowptr, const int2* __restrict__ pack,
    float* __restrict__ ZS, unsigned short* __restrict__ ZH,
    short* __restrict__ Zb1, short* __restrict__ Zb2, int k){
  int wlocal = __builtin_amdgcn_readfirstlane(threadIdx.x>>6);
  int wid = blockIdx.x*4 + wlocal;
  if(wid>=NN) return;
  int l = threadIdx.x&63;
  int ch; bool act;
  if(MODE==0){ ch=48+2*l; act=(l<16); }
  else if(MODE==1){
    if(l<16) ch=2*l; else if(l<24) ch=32+2*(l-16); else ch=48+2*(l-24);
    act=(l<40);
  } else {
    if(l<16) ch=2*l; else ch=32+2*(l-16);
    act=(l<24);
  }
  if(!act) ch=(MODE==2)?0:48;
  int cin_h = (k-1)*96 + ch;
  int base,width,cloc;
  if(ch<32){ base=0; width=32; cloc=ch; }
  else if(ch<48){ base=160; width=16; cloc=ch-32; }
  else { base=240; width=32; cloc=ch-48; }
  int cout = base + k*width + cloc;
  int cpp  = base + (k-2)*width + cloc;
  const unsigned short* __restrict__ Zc = ZH + cin_h;
  int e0=rowptr[wid], e1=rowptr[wid+1];
  float accx=0.f, accy=0.f;
  int e=e0;
  for(; e+16<=e1; e+=16){
    float w[16]; unsigned z[16];
    #pragma unroll
    for(int j=0;j<16;j++){
      int2 p=pack[e+j];
      w[j]=__int_as_float(p.y);
      z[j]=*(const unsigned*)&Zc[(unsigned)p.x*SZH];
    }
    #pragma unroll
    for(int j=0;j<16;j++){
      accx += h2f((unsigned short)(z[j]&0xffffu))*w[j];
      accy += h2f((unsigned short)(z[j]>>16))*w[j];
    }
  }
  for(; e+4<=e1; e+=4){
    float w[4]; unsigned z[4];
    #pragma unroll
    for(int j=0;j<4;j++){ int2 p=pack[e+j]; w[j]=__int_as_float(p.y); z[j]=*(const unsigned*)&Zc[(unsigned)p.x*SZH]; }
    #pragma unroll
    for(int j=0;j<4;j++){
      accx += h2f((unsigned short)(z[j]&0xffffu))*w[j];
      accy += h2f((unsigned short)(z[j]>>16))*w[j];
    }
  }
  for(; e<e1; ++e){
    int2 p=pack[e];
    unsigned zz=*(const unsigned*)&Zc[(unsigned)p.x*SZH];
    float ww=__int_as_float(p.y);
    accx += h2f((unsigned short)(zz&0xffffu))*ww;
    accy += h2f((unsigned short)(zz>>16))*ww;
  }
  if(act){
    float alpha=(k==1)?1.f:2.f;
    float vx = -alpha*accx, vy = -alpha*accy;
    if(k>=2){
      float2 pp=*(const float2*)&ZS[(unsigned)wid*SZS+cpp];
      vx -= pp.x; vy -= pp.y;
    }
    *(float2*)&ZS[(unsigned)wid*SZS+cout]=make_float2(vx,vy);
    unsigned hh = pack2h(vx,vy);
    if(k<=3) *(unsigned*)&ZH[(size_t)wid*SZH + k*96 + ch] = hh;
    if(ch<48) *(unsigned*)&Zb2[fragidx(8,wid,cout)] = hh;
    else      *(unsigned*)&Zb1[fragidx(5,wid,cout-240)] = hh;
  }
}

// G1: A = [T(x(t)) (Zb1) | T(h1(t-1)) (Zb2 kt0..4)], K=320, fp16 MFMA. Fused LSTM layer-1 epilogue.
__global__ __launch_bounds__(256) void k_gemm1(const short* Zb1r, const short* Zb2r, const short* __restrict__ Wpk,
        const float* __restrict__ Bc, const float* __restrict__ wc1,
        float* __restrict__ c1, float* __restrict__ ZS, unsigned short* __restrict__ ZH,
        short* Zb1w, short* Zb2w, const float* __restrict__ xn){
  int wv=threadIdx.x>>6, lane=threadIdx.x&63;
  int tile=blockIdx.x*4+wv;
  if(tile>=625) return;
  const v8s* A1=(const v8s*)Zb1r + (size_t)tile*320 + lane;
  const v8s* A2=(const v8s*)Zb2r + (size_t)tile*512 + lane;
  v8h afr[10];
  #pragma unroll
  for(int kt=0;kt<5;kt++){
    afr[kt]  =__builtin_bit_cast(v8h, A1[kt*64]);
    afr[5+kt]=__builtin_bit_cast(v8h, A2[kt*64]);
  }
  const v8s* Wp=(const v8s*)Wpk;
  v4f acc[8];
  #pragma unroll
  for(int nt=0;nt<8;nt++) acc[nt]=(v4f){0.f,0.f,0.f,0.f};
  #pragma unroll
  for(int kt=0;kt<10;kt++){
    #pragma unroll
    for(int nt=0;nt<8;nt++){
      v8h b=__builtin_bit_cast(v8h, Wp[(kt*8+nt)*64+lane]);
      acc[nt]=__builtin_amdgcn_mfma_f32_16x16x32_f16(afr[kt],b,acc[nt],0,0,0);
    }
  }
  int row0=tile*16;
  int j0=lane&15;
  int r0=row0+(lane>>4)*4;
  #pragma unroll
  for(int reg=0;reg<4;reg++){
    int row=r0+reg;
    #pragma unroll
    for(int jj=0;jj<2;jj++){
      int j=jj*16+j0;
      float c=c1[row*32+j];
      float I =sigmf(acc[0+jj][reg]+Bc[j]      + wc1[j]*c);
      float Fg=sigmf(acc[2+jj][reg]+Bc[32+j]   + wc1[32+j]*c);
      float Ct=tanhf(acc[4+jj][reg]+Bc[64+j]);
      float Cn=Fg*c + I*Ct;
      float O =sigmf(acc[6+jj][reg]+Bc[96+j]   + wc1[64+j]*Cn);
      float h =O*tanhf(Cn);
      c1[row*32+j]=Cn;
      ZS[(size_t)row*SZS + j]=h;                 // h1 T0 f32
      ZH[(size_t)row*SZH + j]=f2h(h);            // level0 h1
      Zb2w[fragidx(8,row,j)]=(short)f2h(h);      // h1 T0 fragment
    }
    if(xn){
      float2 xv=*(const float2*)&xn[(size_t)row*32 + 2*j0];
      *(float2*)&ZS[(size_t)row*SZS + 240 + 2*j0]=xv;
      unsigned pr=pack2h(xv.x,xv.y);
      *(unsigned*)&ZH[(size_t)row*SZH + 48 + 2*j0]=pr;
      *(unsigned*)&Zb1w[fragidx(5,row,2*j0)]=pr;
    }
  }
}

// G2: A = Zb2 (K=256 incl pad), fp16 MFMA. Fused LSTM layer-2 epilogue (+pool on last step).
__global__ __launch_bounds__(256) void k_gemm2(const short* Zb2r, const short* __restrict__ Wpk,
        const float* __restrict__ Bc, const float* __restrict__ wc2,
        float* __restrict__ c2, float* __restrict__ ZS, unsigned short* __restrict__ ZH,
        short* Zb2w, float* __restrict__ u, const int* __restrict__ batch, int last){
  int wv=threadIdx.x>>6, lane=threadIdx.x&63;
  int tile=blockIdx.x*4+wv;
  if(tile>=625) return;
  const v8s* Az=(const v8s*)Zb2r + (size_t)tile*512 + lane;
  v8h afr[8];
  #pragma unroll
  for(int kt=0;kt<8;kt++) afr[kt]=__builtin_bit_cast(v8h, Az[kt*64]);
  const v8s* Wp=(const v8s*)Wpk;
  v4f acc[4];
  #pragma unroll
  for(int nt=0;nt<4;nt++) acc[nt]=(v4f){0.f,0.f,0.f,0.f};
  #pragma unroll
  for(int kt=0;kt<8;kt++){
    #pragma unroll
    for(int nt=0;nt<4;nt++){
      v8h b=__builtin_bit_cast(v8h, Wp[(kt*4+nt)*64+lane]);
      acc[nt]=__builtin_amdgcn_mfma_f32_16x16x32_f16(afr[kt],b,acc[nt],0,0,0);
    }
  }
  int row0=tile*16;
  int j=lane&15;
  int r0=row0+(lane>>4)*4;
  #pragma unroll
  for(int reg=0;reg<4;reg++){
    int row=r0+reg;
    float c=c2[row*16+j];
    float I =sigmf(acc[0][reg]+Bc[j]    +wc2[j]*c);
    float Fg=sigmf(acc[1][reg]+Bc[16+j] +wc2[16+j]*c);
    float Ct=tanhf(acc[2][reg]+Bc[32+j]);
    float Cn=Fg*c+I*Ct;
    float O =sigmf(acc[3][reg]+Bc[48+j] +wc2[32+j]*Cn);
    float h =O*tanhf(Cn);
    c2[row*16+j]=Cn;
    ZS[(size_t)row*SZS + 160 + j]=h;             // h2 T0 f32
    ZH[(size_t)row*SZH + 32 + j]=f2h(h);         // level0 h2
    Zb2w[fragidx(8,row,160+j)]=(short)f2h(h);    // h2 T0 fragment
    if(last) atomicAdd(&u[batch[row]*16+j], h);
  }
}

// ---------- readout ----------
__global__ void k_final(const float* __restrict__ u, const float* __restrict__ lw, const float* __restrict__ lb,
                        float* __restrict__ out){
  int g=threadIdx.x;
  if(g<NG){
    float s=lb[0];
    #pragma unroll
    for(int j=0;j<16;j++) s += u[g*16+j]*lw[j];
    out[g]=s;
  }
}

extern "C" void kernel_launch(void* const* d_in, const int* in_sizes, int n_in,
                              void* d_out, int out_size, void* d_ws, size_t ws_size,
                              hipStream_t stream){
  const float* x   = (const float*)d_in[0];
  const int*   ei  = (const int*)d_in[1];
  const float* ea  = (const float*)d_in[2];
  const int*   bat = (const int*)d_in[3];
  const float* Wx1=(const float*)d_in[4];  const float* bx1=(const float*)d_in[5];
  const float* Wh1=(const float*)d_in[6];  const float* bh1=(const float*)d_in[7];
  const float* wc1=(const float*)d_in[8];  const float* b1 =(const float*)d_in[9];
  const float* Wx2=(const float*)d_in[10]; const float* bx2=(const float*)d_in[11];
  const float* Wh2=(const float*)d_in[12]; const float* bh2=(const float*)d_in[13];
  const float* wc2=(const float*)d_in[14]; const float* b2 =(const float*)d_in[15];
  const float* lw =(const float*)d_in[16]; const float* lb =(const float*)d_in[17];
  const int* src = ei; const int* dst = ei+EE;

  float* ws = (float*)d_ws;
  size_t off=0;
  auto alloc=[&](size_t n)->float*{ float* p=ws+off; off+=(n+15)&~(size_t)15; return p; };
  // zeroed region: deg, c1, c2, u, cnt, ZS, ZH, Zb1, Zb2
  float* deg=alloc(NN);
  float* c1=alloc((size_t)NN*32);
  float* c2=alloc((size_t)NN*16);
  float* u =alloc(NG*16);
  int*   cnt=(int*)alloc(NN);
  float* ZS=alloc((size_t)NN*SZS);
  unsigned short* ZH=(unsigned short*)alloc((size_t)NN*SZH/2);
  short* Zb1=(short*)alloc(625*5*64*8/2);
  short* Zb2=(short*)alloc(625*8*64*8/2);
  size_t zeroEnd=off;
  float* dis=alloc(NN);
  float* wnorm=alloc(EE);
  int*   rowptr=(int*)alloc(NN+1);
  int*   wp=(int*)alloc(NN);
  int2*  pack=(int2*)alloc((size_t)EE*2);
  short* Wpk1=(short*)alloc(5120*4);
  short* Wpk2=(short*)alloc(2048*4);
  float* Bc1=alloc(128);     float* Bc2=alloc(64);
  (void)ws_size; (void)in_sizes; (void)n_in; (void)out_size;

  hipMemsetAsync(d_ws, 0, zeroEnd*sizeof(float), stream);
  k_deg    <<<1250,256,0,stream>>>(src,ea,deg);
  k_dis    <<<40,256,0,stream>>>(deg,dis);
  k_wnorm  <<<1250,256,0,stream>>>(src,dst,ea,dis,wnorm,cnt);
  k_scan   <<<1,1024,0,stream>>>(cnt,rowptr,wp);
  k_scatter<<<1250,256,0,stream>>>(src,dst,wnorm,wp,pack);
  k_wreorg <<<29,256,0,stream>>>(Wx1,bx1,Wh1,bh1,b1,Wx2,bx2,Wh2,bh2,b2,Wpk1,Wpk2,Bc1,Bc2);

  k_init1<<<313,256,0,stream>>>(x, ZS, ZH, Zb1);
  for(int k=1;k<5;k++)
    k_spmm<0><<<2500,256,0,stream>>>(rowptr,pack,ZS,ZH,Zb1,Zb2,k);   // T_k(x(0))

  for(int t=0;t<TT;t++){
    k_gemm1<<<157,256,0,stream>>>(Zb1,Zb2,Wpk1,Bc1,wc1,c1,ZS,ZH,Zb1,Zb2,
          (t<TT-1)? x+(size_t)(t+1)*NN*32 : nullptr);
    if(t<TT-1){
      for(int k=1;k<5;k++)
        k_spmm<1><<<2500,256,0,stream>>>(rowptr,pack,ZS,ZH,Zb1,Zb2,k); // T_k(h1(t)), T_k(h2(t-1)), T_k(x(t+1))
    } else {
      for(int k=1;k<5;k++)
        k_spmm<2><<<2500,256,0,stream>>>(rowptr,pack,ZS,ZH,Zb1,Zb2,k); // no x-chain on last step
    }
    k_gemm2<<<157,256,0,stream>>>(Zb2,Wpk2,Bc2,wc2,c2,ZS,ZH,Zb2,u,bat,(t==TT-1)?1:0);
  }
  k_final<<<1,64,0,stream>>>(u,lw,lb,(float*)d_out);
}